// Round 1
// baseline (524.648 us; speedup 1.0000x reference)
//
#include <hip/hip_runtime.h>

#define N_BATCH 256
#define SEQ     2048
#define L       50
#define CHUNK   64
#define HALO    3
#define RROWS   (CHUNK + 2 * HALO)   // 70 slots: seq s0-3 .. s0+66
#define SQ      68                   // q row stride in floats (272 B, 16B-aligned, 2-way banks)
#define SP      72                   // p row stride in bf16   (144 B, 16B-aligned, 2-way banks)
#define SB      72                   // B row stride in bf16
#define ITER    3

typedef __attribute__((ext_vector_type(8))) short        bf16x8;
typedef __attribute__((ext_vector_type(4))) float        f32x4;
typedef __attribute__((ext_vector_type(4))) unsigned int uint4v;

__device__ __forceinline__ unsigned short f2b(float f) {
    unsigned int u = __builtin_bit_cast(unsigned int, f);
    u += 0x7FFFu + ((u >> 16) & 1u);            // round-to-nearest-even
    return (unsigned short)(u >> 16);
}

__global__ __launch_bounds__(256, 3) void mfvi_kernel(
    const float* __restrict__ unary,
    const float* __restrict__ mask,
    const float* __restrict__ trans,   // [L][L]
    const float* __restrict__ tstart,  // [L]
    const float* __restrict__ tend,    // [L]
    float* __restrict__ out)
{
    __shared__ __attribute__((aligned(16))) float          q_s[RROWS * SQ];
    __shared__ __attribute__((aligned(16))) unsigned short p_s[RROWS * SP];
    __shared__ __attribute__((aligned(16))) unsigned short BLs[64 * SB];  // BL[n][k] = T[k][n]
    __shared__ __attribute__((aligned(16))) unsigned short BRs[64 * SB];  // BR[n][k] = T[n][k]
    __shared__ float mask_s[RROWS];
    __shared__ float ts_s[64], te_s[64];

    const int tid  = threadIdx.x;
    const int lane = tid & 63;
    const int wave = tid >> 6;
    const int nloc = lane & 15;
    const int quad = lane >> 4;
    const int s0   = blockIdx.x * CHUNK;
    const int nb   = blockIdx.y;

    // ---------------- phase A: constants into LDS ----------------
    for (int i = tid; i < 64 * 64; i += 256) {
        int nn = i >> 6, kk = i & 63;
        float vl = 0.f, vr = 0.f;
        if (nn < L && kk < L) {
            vl = trans[kk * L + nn];
            vr = trans[nn * L + kk];
        }
        BLs[nn * SB + kk] = f2b(vl);
        BRs[nn * SB + kk] = f2b(vr);
    }
    if (tid < 64) {
        ts_s[tid] = (tid < L) ? tstart[tid] : 0.f;
        te_s[tid] = (tid < L) ? tend[tid]   : 0.f;
    }
    if (tid < RROWS) {
        int s = s0 - HALO + tid;
        mask_s[tid] = (s >= 0 && s < SEQ) ? mask[nb * SEQ + s] : 0.f;
    }
    // zero entire p buffer (out-of-seq rows stay 0 forever -> boundary matvec = 0)
    for (int i = tid; i < (RROWS * SP) / 2; i += 256)
        ((unsigned int*)p_s)[i] = 0u;
    __syncthreads();

    // ---------------- phase B: q init = unary*mask (fp32), pad=0 ----------------
    for (int i = tid; i < RROWS * 64; i += 256) {
        int slot = i >> 6, c = i & 63;
        int s = s0 - HALO + slot;
        float v = 0.f;
        if (c < L && s >= 0 && s < SEQ)
            v = unary[(nb * SEQ + s) * L + c] * mask_s[slot];
        q_s[slot * SQ + c] = v;
    }

    // B fragments -> registers, held for whole kernel (64 VGPRs)
    bf16x8 bL[2][4], bR[2][4];
#pragma unroll
    for (int kk = 0; kk < 2; ++kk) {
#pragma unroll
        for (int nt = 0; nt < 4; ++nt) {
            int nrow = nt * 16 + nloc;
            int koff = kk * 32 + quad * 8;
            bL[kk][nt] = *(const bf16x8*)&BLs[nrow * SB + koff];
            bR[kk][nt] = *(const bf16x8*)&BRs[nrow * SB + koff];
        }
    }

    // ---------------- iterations ----------------
    for (int it = 0; it < ITER; ++it) {
        __syncthreads();   // q ready (init or previous epilogue)

        // softmax: 4 lanes per row, 16 channels each. valid slots: [it, RROWS-it) & in-seq
        {
            const int part  = tid & 3;
            const int rbase = tid >> 2;
#pragma unroll
            for (int base = 0; base < RROWS; base += 64) {
                int slot = base + rbase;
                int s = s0 - HALO + slot;
                bool valid = (slot < RROWS) && (slot >= it) && (slot < RROWS - it)
                             && (s >= 0) && (s < SEQ);
                if (valid) {
                    float x[16];
                    const f32x4* src = (const f32x4*)&q_s[slot * SQ + part * 16];
#pragma unroll
                    for (int k = 0; k < 4; ++k) {
                        f32x4 t4 = src[k];
#pragma unroll
                        for (int j = 0; j < 4; ++j) x[4 * k + j] = t4[j];
                    }
                    float mx = -1e30f;
#pragma unroll
                    for (int j = 0; j < 16; ++j)
                        if (part * 16 + j < L) mx = fmaxf(mx, x[j]);
                    mx = fmaxf(mx, __shfl_xor(mx, 1, 64));
                    mx = fmaxf(mx, __shfl_xor(mx, 2, 64));
                    float e[16];
                    float sum = 0.f;
#pragma unroll
                    for (int j = 0; j < 16; ++j) {
                        float ev = (part * 16 + j < L) ? __expf(x[j] - mx) : 0.f;
                        e[j] = ev;
                        sum += ev;
                    }
                    sum += __shfl_xor(sum, 1, 64);
                    sum += __shfl_xor(sum, 2, 64);
                    float inv = 1.0f / sum;
                    unsigned int w[8];
#pragma unroll
                    for (int j2 = 0; j2 < 8; ++j2) {
                        unsigned int lo = f2b(e[2 * j2] * inv);
                        unsigned int hi = f2b(e[2 * j2 + 1] * inv);
                        w[j2] = lo | (hi << 16);
                    }
                    uint4v* dst = (uint4v*)&p_s[slot * SP + part * 16];
                    uint4v w0, w1;
                    w0[0] = w[0]; w0[1] = w[1]; w0[2] = w[2]; w0[3] = w[3];
                    w1[0] = w[4]; w1[1] = w[5]; w1[2] = w[6]; w1[3] = w[7];
                    dst[0] = w0;
                    dst[1] = w1;
                }
            }
        }
        __syncthreads();   // p ready

        // MFMA phase: new q = unary*mask + p[r-1]@T + p[r+1]@T^T + bnd, all * mask
        int cs = s0 - 2 + it;      if (cs < 0)   cs = 0;
        int ce = s0 + CHUNK + 2 - it; if (ce > SEQ) ce = SEQ;
        int ntiles = (ce - cs + 15) >> 4;
        for (int t = wave; t < ntiles; t += 4) {
            int rbase_seq = cs + t * 16;
            int arow = rbase_seq + nloc;                     // A-frag row: m = lane&15
            int slotL = arow - 1 - (s0 - HALO);
            int slotR = arow + 1 - (s0 - HALO);
            if (slotL < 0) slotL = 0;           if (slotL > RROWS - 1) slotL = RROWS - 1;
            if (slotR < 0) slotR = 0;           if (slotR > RROWS - 1) slotR = RROWS - 1;

            f32x4 acc[4];
#pragma unroll
            for (int nt = 0; nt < 4; ++nt) { acc[nt][0] = 0.f; acc[nt][1] = 0.f; acc[nt][2] = 0.f; acc[nt][3] = 0.f; }

#pragma unroll
            for (int kk = 0; kk < 2; ++kk) {
                bf16x8 aL = *(const bf16x8*)&p_s[slotL * SP + kk * 32 + quad * 8];
                bf16x8 aR = *(const bf16x8*)&p_s[slotR * SP + kk * 32 + quad * 8];
#pragma unroll
                for (int nt = 0; nt < 4; ++nt) {
                    acc[nt] = __builtin_amdgcn_mfma_f32_16x16x32_bf16(aL, bL[kk][nt], acc[nt], 0, 0, 0);
                    acc[nt] = __builtin_amdgcn_mfma_f32_16x16x32_bf16(aR, bR[kk][nt], acc[nt], 0, 0, 0);
                }
            }

            // epilogue: D row = quad*4+reg, col = lane&15 (+16*nt)
#pragma unroll
            for (int nt = 0; nt < 4; ++nt) {
                int c = nt * 16 + nloc;
#pragma unroll
                for (int reg = 0; reg < 4; ++reg) {
                    int srow = rbase_seq + quad * 4 + reg;
                    if (c < L && srow < ce) {
                        int slot = srow - (s0 - HALO);
                        float mk = mask_s[slot];
                        float v  = unary[(nb * SEQ + srow) * L + c] * mk + acc[nt][reg];
                        if (srow == 0) v += ts_s[c];
                        if (srow >= 1) v += te_s[c];
                        v *= mk;
                        q_s[slot * SQ + c] = v;
                    }
                }
            }
        }
    }
    __syncthreads();

    // ---------------- store ----------------
    for (int i = tid; i < CHUNK * L; i += 256) {
        int r = i / L;
        int c = i - r * L;
        int s = s0 + r;
        if (s < SEQ)
            out[(nb * SEQ + s) * L + c] = q_s[(r + HALO) * SQ + c];
    }
}

extern "C" void kernel_launch(void* const* d_in, const int* in_sizes, int n_in,
                              void* d_out, int out_size, void* d_ws, size_t ws_size,
                              hipStream_t stream) {
    const float* unary  = (const float*)d_in[0];
    const float* mask   = (const float*)d_in[1];
    const float* trans  = (const float*)d_in[2];
    const float* tstart = (const float*)d_in[3];
    const float* tend   = (const float*)d_in[4];
    float* out = (float*)d_out;

    dim3 grid((SEQ + CHUNK - 1) / CHUNK, N_BATCH);
    mfvi_kernel<<<grid, dim3(256), 0, stream>>>(unary, mask, trans, tstart, tend, out);
}

// Round 2
// 442.858 us; speedup vs baseline: 1.1847x; 1.1847x over previous
//
#include <hip/hip_runtime.h>

#define N_BATCH 256
#define SEQ     2048
#define L       50
#define CORE    58                  // output rows per block
#define HALO    3                   // iteration dependency radius
#define WROWS   64                  // working rows = 4 tiles x 16
#define SP      72                  // p_s row stride in bf16 (144 B, 16B-aligned)
#define SB      72                  // B row stride in bf16
#define ITER    3

typedef __attribute__((ext_vector_type(8))) short bf16x8;
typedef __attribute__((ext_vector_type(4))) float f32x4;

__device__ __forceinline__ unsigned short f2b(float f) {
    unsigned int u = __builtin_bit_cast(unsigned int, f);
    u += 0x7FFFu + ((u >> 16) & 1u);            // RTNE
    return (unsigned short)(u >> 16);
}

__global__ __launch_bounds__(256, 4) void mfvi_kernel(
    const float* __restrict__ unary,
    const float* __restrict__ mask,
    const float* __restrict__ trans,   // [L][L]
    const float* __restrict__ tstart,  // [L]
    const float* __restrict__ tend,    // [L]
    float* __restrict__ out)
{
    __shared__ __attribute__((aligned(16))) unsigned short p_s[WROWS * SP]; // 9.2 KB
    __shared__ __attribute__((aligned(16))) unsigned short BLs[64 * SB];    // 9.2 KB
    __shared__ __attribute__((aligned(16))) unsigned short BRs[64 * SB];    // 9.2 KB
    __shared__ float ts_s[64], te_s[64];

    const int tid   = threadIdx.x;
    const int lane  = tid & 63;
    const int wave  = tid >> 6;
    const int nloc  = lane & 15;
    const int quad  = lane >> 4;
    const int nb    = blockIdx.y;
    const int s0    = blockIdx.x * CORE;
    const int tile0 = s0 - HALO + wave * 16;   // global seq row of this wave's tile row 0

    // ---------- stage transitions: coalesced global read, scatter to LDS ----------
    for (int i = tid; i < L * L; i += 256) {
        int r = i / L, c = i - r * L;
        unsigned short v = f2b(trans[i]);
        BLs[c * SB + r] = v;   // left msg  B[k][n] = T[k][n], stored [n][k]
        BRs[r * SB + c] = v;   // right msg B[k][n] = T[n][k], stored [n][k]
    }
    // zero K-padding (k in [L,64)) for all n-rows: A cols there are 0, avoid 0*NaN
    if (tid < 128) {
        unsigned short* p = (tid < 64 ? BLs : BRs) + (tid & 63) * SB;
        for (int k = L; k < 64; ++k) p[k] = 0;
    }
    if (tid < 64) {
        ts_s[tid] = (tid < L) ? tstart[tid] : 0.f;
        te_s[tid] = (tid < L) ? tend[tid]   : 0.f;
    }
    __syncthreads();

    // ---------- persistent registers ----------
    bf16x8 bL[2][4], bR[2][4];                 // 64 VGPRs, held for whole kernel
#pragma unroll
    for (int kk = 0; kk < 2; ++kk)
#pragma unroll
        for (int nt = 0; nt < 4; ++nt) {
            int off = (nt * 16 + nloc) * SB + kk * 32 + quad * 8;
            bL[kk][nt] = *(const bf16x8*)&BLs[off];
            bR[kk][nt] = *(const bf16x8*)&BRs[off];
        }
    float ts_r[4], te_r[4];
#pragma unroll
    for (int nt = 0; nt < 4; ++nt) {
        ts_r[nt] = ts_s[nt * 16 + nloc];
        te_r[nt] = te_s[nt * 16 + nloc];
    }

    // q, unary*mask, mask in MFMA C-layout: row = quad*4+reg, col = nt*16+nloc
    float q[4][4], um[4][4], mk[4];
#pragma unroll
    for (int reg = 0; reg < 4; ++reg) {
        int g = tile0 + quad * 4 + reg;
        bool in = (g >= 0) && (g < SEQ);
        mk[reg] = in ? mask[nb * SEQ + g] : 0.f;
#pragma unroll
        for (int nt = 0; nt < 4; ++nt) {
            int c = nt * 16 + nloc;
            float u = (in && c < L) ? unary[(nb * SEQ + g) * L + c] : 0.f;
            um[nt][reg] = u * mk[reg];
            q[nt][reg]  = um[nt][reg];
        }
    }

    const int myrow = wave * 16 + quad * 4;                       // p_s slot base
    int slL = wave * 16 + nloc - 1; if (slL < 0)  slL = 0;        // don't-care rows only
    int slR = wave * 16 + nloc + 1; if (slR > 63) slR = 63;

    // ---------- iterations: global-free ----------
    for (int it = 0; it < ITER; ++it) {
        // softmax in registers -> p_s (bf16, A-layout). Row lives on 16 nloc-lanes.
        const bool v3 = (nloc < 2);                                // col 48+nloc < 50
#pragma unroll
        for (int reg = 0; reg < 4; ++reg) {
            float x0 = q[0][reg], x1 = q[1][reg], x2 = q[2][reg];
            float x3 = v3 ? q[3][reg] : -1e30f;
            float m = fmaxf(fmaxf(x0, x1), fmaxf(x2, x3));
            m = fmaxf(m, __shfl_xor(m, 1, 64));
            m = fmaxf(m, __shfl_xor(m, 2, 64));
            m = fmaxf(m, __shfl_xor(m, 4, 64));
            m = fmaxf(m, __shfl_xor(m, 8, 64));
            float e0 = __expf(x0 - m), e1 = __expf(x1 - m);
            float e2 = __expf(x2 - m), e3 = __expf(x3 - m);      // e3=0 when !v3
            float s = e0 + e1 + e2 + e3;
            s += __shfl_xor(s, 1, 64);
            s += __shfl_xor(s, 2, 64);
            s += __shfl_xor(s, 4, 64);
            s += __shfl_xor(s, 8, 64);
            int g = tile0 + quad * 4 + reg;
            float inv = ((g >= 0) && (g < SEQ)) ? __builtin_amdgcn_rcpf(s) : 0.f;
            unsigned short* row = &p_s[(myrow + reg) * SP];
            row[nloc]      = f2b(e0 * inv);
            row[16 + nloc] = f2b(e1 * inv);
            row[32 + nloc] = f2b(e2 * inv);
            row[48 + nloc] = f2b(e3 * inv);                       // 0 for cols >= 50
        }
        __syncthreads();   // p ready

        // messages: D[m][n] = sum_k p[g-1][k] T[k][n] + p[g+1][k] T[n][k]
        f32x4 acc[4];
#pragma unroll
        for (int nt = 0; nt < 4; ++nt) {
            acc[nt][0] = 0.f; acc[nt][1] = 0.f; acc[nt][2] = 0.f; acc[nt][3] = 0.f;
        }
#pragma unroll
        for (int kk = 0; kk < 2; ++kk) {
            bf16x8 aL = *(const bf16x8*)&p_s[slL * SP + kk * 32 + quad * 8];
            bf16x8 aR = *(const bf16x8*)&p_s[slR * SP + kk * 32 + quad * 8];
#pragma unroll
            for (int nt = 0; nt < 4; ++nt) {
                acc[nt] = __builtin_amdgcn_mfma_f32_16x16x32_bf16(aL, bL[kk][nt], acc[nt], 0, 0, 0);
                acc[nt] = __builtin_amdgcn_mfma_f32_16x16x32_bf16(aR, bR[kk][nt], acc[nt], 0, 0, 0);
            }
        }
        __syncthreads();   // p_s reads done before next iteration's writes

        // epilogue (pure VALU): q = (um + msgs + boundary) * mask
#pragma unroll
        for (int reg = 0; reg < 4; ++reg) {
            int g = tile0 + quad * 4 + reg;
#pragma unroll
            for (int nt = 0; nt < 4; ++nt) {
                float v = um[nt][reg] + acc[nt][reg];
                if (g == 0) v += ts_r[nt];
                if (g >= 1) v += te_r[nt];
                q[nt][reg] = v * mk[reg];
            }
        }
    }

    // ---------- store core rows ----------
#pragma unroll
    for (int reg = 0; reg < 4; ++reg) {
        int g = tile0 + quad * 4 + reg;
        if (g >= s0 && g < s0 + CORE && g < SEQ) {
#pragma unroll
            for (int nt = 0; nt < 4; ++nt) {
                int c = nt * 16 + nloc;
                if (c < L) out[(nb * SEQ + g) * L + c] = q[nt][reg];
            }
        }
    }
}

extern "C" void kernel_launch(void* const* d_in, const int* in_sizes, int n_in,
                              void* d_out, int out_size, void* d_ws, size_t ws_size,
                              hipStream_t stream) {
    const float* unary  = (const float*)d_in[0];
    const float* mask   = (const float*)d_in[1];
    const float* trans  = (const float*)d_in[2];
    const float* tstart = (const float*)d_in[3];
    const float* tend   = (const float*)d_in[4];
    float* out = (float*)d_out;

    dim3 grid((SEQ + CORE - 1) / CORE, N_BATCH);   // 36 x 256
    mfvi_kernel<<<grid, dim3(256), 0, stream>>>(unary, mask, trans, tstart, tend, out);
}